// Round 6
// baseline (114.582 us; speedup 1.0000x reference)
//
#include <hip/hip_runtime.h>

// NeRF fused kernel for MI355X (gfx950) — round 11: SINGLE KERNEL, NO WORKSPACE.
// Round 10 post-mortem: main stuck 38-43us across rounds 6-10 (MfmaUtil ~37%)
// regardless of occupancy/rotation — but the BENCH is 107.9us: main 42 +
// 41.8us harness fillBufferAligned (268MB poison of the workspace we request,
// on the timed stream, every iteration) + setup + 2 launch gaps.
// Round 11: drop d_ws entirely. Each block prepares its own W2/W3 frags:
//   A) stage W2 f32->f16 into a bank-swizzled linear LDS image
//      (byte = k*256 + 2n ^ ((n>>5)&3)<<5 — XOR spreads the later
//      column-gather from 16-way to ~4-way conflicts); W3 frags + b2 direct.
//   B) barrier; LDS->LDS scatter into the EXACT frag layout verified since
//      round 4 (same RNE (f16) casts -> bit-identical weight values).
//   C) barrier; round-10 main loop verbatim (rolled ks3 + rotation, (512,4)).
// Linear image (32KB) is UNIONED with f_lds (post-loop only): LDS 72.5KB ->
// same 2 blocks/CU as round 10. W2/W3 global re-reads are L2-resident
// (135MB @ ~3TB/s aggregate, well under the 34.5TB/s L2 ceiling).
// Permutation identity (HW-verified rounds 4-10):
//   h2 feature(slot) = 32*quad + mt*4 + r  (phase-2 D)  =  32*quad + ks3*8 + j
//   (phase-3 B), so phase-2 output regs ARE phase-3 B-frags.

typedef _Float16 f16;
typedef __attribute__((ext_vector_type(2))) _Float16 h2v;
typedef __attribute__((ext_vector_type(8))) _Float16 half8;
typedef __attribute__((ext_vector_type(4))) float floatx4;

#define H 128
#define NS 64

static __device__ __forceinline__ h2v pkrtz(float a, float b) {
  return __builtin_bit_cast(h2v, __builtin_amdgcn_cvt_pkrtz(a, b));
}

// x += dpp_shifted(x) with 0-fill; CTRL/RM compile-time (builtin needs ICE).
template <int CTRL, int RM>
static __device__ __forceinline__ float dpp_add(float x) {
  int sh = __builtin_amdgcn_update_dpp(0, __builtin_bit_cast(int, x),
                                       CTRL, RM, 0xf, false);
  return x + __builtin_bit_cast(float, sh);
}

// Wave64 inclusive add-scan, pure VALU (classic gfx9 sequence).
static __device__ __forceinline__ float wave_iscan(float x) {
  x = dpp_add<0x111, 0xf>(x);   // row_shr:1
  x = dpp_add<0x112, 0xf>(x);   // row_shr:2
  x = dpp_add<0x114, 0xf>(x);   // row_shr:4
  x = dpp_add<0x118, 0xf>(x);   // row_shr:8
  x = dpp_add<0x142, 0xa>(x);   // row_bcast:15 -> rows 1,3
  x = dpp_add<0x143, 0xc>(x);   // row_bcast:31 -> rows 2,3
  return x;
}

// ---------------------------------------------------------------------------
// Single kernel: block = 8 rays = 8 waves; wave = 1 ray = 64 points.
// Two barriers (stage->scatter, scatter->main); no other cross-wave deps.
// ---------------------------------------------------------------------------
__global__ __launch_bounds__(512, 4) void nerf_all(
    const float* __restrict__ origins, const float* __restrict__ dirs,
    const float* __restrict__ W1, const float* __restrict__ b1,
    const float* __restrict__ W2, const float* __restrict__ b2,
    const float* __restrict__ W3, const float* __restrict__ b3,
    float* __restrict__ out)
{
  __shared__ __align__(16) half8 w_frag[2304];    // 36 KB: W2 frags [0..2047], W3 [2048..2303]
  __shared__ __align__(16) float b2_lds[H];       // 512 B
  __shared__ __align__(16) f16   popd[8][2][H];   // per-wave po/pd strips (4 KB)
  __shared__ __align__(16) char  uni[32768];      // w2lin (32KB) | f_lds (8KB, post-loop)

  float (*f_lds)[64][4] = (float (*)[64][4])uni;  // 8*64*4*4 = 8 KB

  const int t = threadIdx.x;
  const int w = t >> 6, lane = t & 63, quad = lane >> 4, l16 = lane & 15;
  const float delta = 4.0f / NS;       // near=2, far=6 baked
  const int ray = blockIdx.x * 8 + w;

  // ---- Phase A: global staging ----
  // W2 f32 -> swizzled linear f16 image: element (k,n) at byte
  //   k*256 + 2n ^ (((n>>5)&3)<<5). RNE (f16) casts, identical to r9/r10.
  {
    const float4* src = (const float4*)W2;        // 4096 float4
    #pragma unroll
    for (int i = 0; i < 8; ++i) {
      const int idx = t + i * 512;
      const float4 v = src[idx];
      const int k = idx >> 5, n0 = (idx & 31) * 4;   // 4 consecutive n, same k
      int byte0 = k * 256 + 2 * n0;
      byte0 ^= ((n0 >> 5) & 3) << 5;                 // n0..n0+3 share n>>5
      h2v p0; p0[0] = (f16)v.x; p0[1] = (f16)v.y;
      h2v p1; p1[0] = (f16)v.z; p1[1] = (f16)v.w;
      *(h2v*)(uni + byte0)     = p0;
      *(h2v*)(uni + byte0 + 4) = p1;
    }
    if (t < 256) {                                // W3 frags (direct, 2KB L2-hot)
      h2v* wf2 = (h2v*)w_frag;
      #pragma unroll
      for (int j = 0; j < 4; ++j) {
        const int u = t + j * 256;                // 0..1023
        const int j2 = u & 3, lu = (u >> 2) & 63, ks = u >> 8;
        const int c = lu & 15;
        const int k3 = 32 * (lu >> 4) + ks * 8 + 2 * j2;
        h2v pr;
        pr[0] = (c < 4) ? (f16)W3[k3 * 4 + c]       : (f16)0.0f;
        pr[1] = (c < 4) ? (f16)W3[(k3 + 1) * 4 + c] : (f16)0.0f;
        wf2[8192 + u] = pr;
      }
    }
    if (t < 32) ((float4*)b2_lds)[t] = ((const float4*)b2)[t];
  }

  // ---- po/pd (popd is NOT aliased with w2lin; own-wave write/read) ----
  {
    const float o0 = origins[ray*3], o1 = origins[ray*3+1], o2 = origins[ray*3+2];
    const float d0 = dirs[ray*3],    d1 = dirs[ray*3+1],    d2 = dirs[ray*3+2];
    const int k0 = lane * 2;
    const float2 wr0 = *(const float2*)&W1[0*H + k0];
    const float2 wr1 = *(const float2*)&W1[1*H + k0];
    const float2 wr2 = *(const float2*)&W1[2*H + k0];
    const float2 bb  = *(const float2*)&b1[k0];
    float poa = fmaf(o2, wr2.x, fmaf(o1, wr1.x, fmaf(o0, wr0.x, bb.x)));
    float pob = fmaf(o2, wr2.y, fmaf(o1, wr1.y, fmaf(o0, wr0.y, bb.y)));
    float pda = fmaf(d2, wr2.x, fmaf(d1, wr1.x, d0 * wr0.x));
    float pdb = fmaf(d2, wr2.y, fmaf(d1, wr1.y, d0 * wr0.y));
    h2v po2; po2[0] = (f16)poa; po2[1] = (f16)pob;
    h2v pd2; pd2[0] = (f16)pda; pd2[1] = (f16)pdb;
    *(h2v*)&popd[w][0][k0] = po2;
    *(h2v*)&popd[w][1][k0] = pd2;
  }

  __syncthreads();                       // bar1: w2lin image complete

  // ---- Phase B: LDS->LDS scatter into frag layout (one-time, ~4-way) ----
  // Frag F (half8): lane lf=F&63, mt=(F>>6)&7, ks=F>>9; K0=ks*32+(lf>>4)*8;
  // n = 32*((lf&15)>>2) + mt*4 + (lf&3); element r = W2[K0+r][n].
  {
    #pragma unroll
    for (int i = 0; i < 4; ++i) {
      const int F = t + i * 512;                  // 0..2047
      const int lf = F & 63, mt = (F >> 6) & 7, ks = F >> 9;
      const int lf16 = lf & 15, g = lf >> 4;
      const int K0 = ks * 32 + g * 8;
      const int n = 32 * (lf16 >> 2) + mt * 4 + (lf16 & 3);
      int rb = 2 * n;
      rb ^= ((n >> 5) & 3) << 5;                  // match staging swizzle
      rb += K0 * 256;
      half8 fr;
      #pragma unroll
      for (int r = 0; r < 8; ++r)
        fr[r] = *(const f16*)(uni + rb + r * 256);
      w_frag[F] = fr;                             // ds_write_b128, 2-way free
    }
  }

  __syncthreads();                       // bar2: frags ready; uni freed for f_lds

  // ---- hb precompute: hb[ks2][tr] = relu(po + m*pd), resident 64 VGPRs ----
  half8 hb[4][4];
  {
    const half8 z8 = (half8)(f16)0.0f;
    half8 m8[4];
    #pragma unroll
    for (int tr = 0; tr < 4; ++tr)
      m8[tr] = (half8)(f16)(2.0f + (tr*16 + l16 + 0.5f) * delta);
    #pragma unroll
    for (int ks = 0; ks < 4; ++ks) {
      const half8 po8 = *(const half8*)&popd[w][0][ks*32 + quad*8];
      const half8 pd8 = *(const half8*)&popd[w][1][ks*32 + quad*8];
      #pragma unroll
      for (int tr = 0; tr < 4; ++tr)
        hb[ks][tr] = __builtin_elementwise_max(pd8 * m8[tr] + po8, z8);
    }
  }

  const half8* w2f = w_frag;             // 2048 frags
  const half8* w3f = w_frag + 2048;      // 256 frags
  const h2v z2 = (h2v)(f16)0.0f;

  // acc3 init = b3 broadcast (quad 0 rows are the only consumed ones; W3
  // cols >=4 are zero-padded so other quads are garbage-but-unused).
  floatx4 acc3[4];
  {
    const float4 b3v = *(const float4*)&b3[0];
    #pragma unroll
    for (int tr = 0; tr < 4; ++tr) {
      acc3[tr][0] = b3v.x; acc3[tr][1] = b3v.y;
      acc3[tr][2] = b3v.z; acc3[tr][3] = b3v.w;
    }
  }

  // ---- Fused phase 2+3, mt-pair outer, ROLLED (4 iters, reg-safe) with
  // per-wave ks3 rotation (acc3 sum commutes). Verbatim round 10. ----
  #pragma unroll 1
  for (int it = 0; it < 4; ++it) {
    const int ks3 = (w + it) & 3;
    const int mt0 = 2 * ks3, mt1 = mt0 + 1;
    // bias fold: acc[mt][tr][r] starts at b2[32*quad + 4*mt + r]
    const float4 bA = *(const float4*)&b2_lds[quad*32 + ks3*8];
    const float4 bB = *(const float4*)&b2_lds[quad*32 + ks3*8 + 4];
    const half8 w3k = w3f[ks3*64 + lane];
    floatx4 accA[4], accB[4];
    #pragma unroll
    for (int tr = 0; tr < 4; ++tr) {
      accA[tr][0] = bA.x; accA[tr][1] = bA.y; accA[tr][2] = bA.z; accA[tr][3] = bA.w;
      accB[tr][0] = bB.x; accB[tr][1] = bB.y; accB[tr][2] = bB.z; accB[tr][3] = bB.w;
    }
    #pragma unroll
    for (int ks2 = 0; ks2 < 4; ++ks2) {
      const half8 wA = w2f[(ks2*8 + mt0)*64 + lane];
      const half8 wB = w2f[(ks2*8 + mt1)*64 + lane];
      #pragma unroll
      for (int tr = 0; tr < 4; ++tr) {
        accA[tr] = __builtin_amdgcn_mfma_f32_16x16x32_f16(wA, hb[ks2][tr], accA[tr], 0, 0, 0);
        accB[tr] = __builtin_amdgcn_mfma_f32_16x16x32_f16(wB, hb[ks2][tr], accB[tr], 0, 0, 0);
      }
    }
    // pack (bias already in acc) + phase-3 MFMA; b covers features
    // 32*quad + 8*ks3 + 0..7 matching W3's permuted rows.
    #pragma unroll
    for (int tr = 0; tr < 4; ++tr) {
      h2v c0 = __builtin_elementwise_max(pkrtz(accA[tr][0], accA[tr][1]), z2);
      h2v c1 = __builtin_elementwise_max(pkrtz(accA[tr][2], accA[tr][3]), z2);
      h2v c2 = __builtin_elementwise_max(pkrtz(accB[tr][0], accB[tr][1]), z2);
      h2v c3 = __builtin_elementwise_max(pkrtz(accB[tr][2], accB[tr][3]), z2);
      half8 b = { c0[0], c0[1], c1[0], c1[1], c2[0], c2[1], c3[0], c3[1] };
      acc3[tr] = __builtin_amdgcn_mfma_f32_16x16x32_f16(w3k, b, acc3[tr], 0, 0, 0);
    }
  }

  // D3: lane holds f[m = quad*4+r][point tr*16+l16]; quad 0 rows 0..3 are
  // (R,G,B,sigma), b3 already folded in. Transpose via f_lds (aliases the
  // dead w2lin image; same wave, no barrier needed).
  if (quad == 0) {
    #pragma unroll
    for (int tr = 0; tr < 4; ++tr) {
      float4 fv;
      fv.x = acc3[tr][0]; fv.y = acc3[tr][1];
      fv.z = acc3[tr][2]; fv.w = acc3[tr][3];
      *(float4*)&f_lds[w][tr*16 + l16][0] = fv;      // ds_write_b128
    }
  }

  // ---- Phase 4: volume rendering, lane = sample; DPP scan, no bpermute ----
  {
    const float4 fv = *(const float4*)&f_lds[w][lane][0];
    const float sigma = fv.w;
    const float alpha = 1.0f - __expf(-sigma * delta);
    const float S  = wave_iscan(sigma);              // inclusive prefix
    const float T  = __expf(-delta * (S - sigma));   // exclusive transmittance
    const float wt = alpha * T;
    const float sr = wave_iscan(wt * fv.x);          // lane 63 = total
    const float sg = wave_iscan(wt * fv.y);
    const float sb = wave_iscan(wt * fv.z);
    if (lane == 63) {
      out[ray*3+0] = sr; out[ray*3+1] = sg; out[ray*3+2] = sb;
    }
  }
}

extern "C" void kernel_launch(void* const* d_in, const int* in_sizes, int n_in,
                              void* d_out, int out_size, void* d_ws, size_t ws_size,
                              hipStream_t stream) {
  const float* origins = (const float*)d_in[0];
  const float* dirs    = (const float*)d_in[1];
  const float* W1      = (const float*)d_in[2];
  const float* b1      = (const float*)d_in[3];
  const float* W2      = (const float*)d_in[4];
  const float* b2      = (const float*)d_in[5];
  const float* W3      = (const float*)d_in[6];
  const float* b3      = (const float*)d_in[7];
  float* out = (float*)d_out;

  // No workspace use: single fused kernel.
  (void)d_ws; (void)ws_size;
  nerf_all<<<16384 / 8, 512, 0, stream>>>(
      origins, dirs, W1, b1, W2, b2, W3, b3, out);
}

// Round 8
// 106.033 us; speedup vs baseline: 1.0806x; 1.0806x over previous
//
#include <hip/hip_runtime.h>

// NeRF fused kernel for MI355X (gfx950) — round 13.
// Round 12 post-mortem: hipLaunchCooperativeKernel never executed under the
// harness's graph capture (output stayed zeroed -> absmax = ref max 4000).
// Persistent/grid-sync direction is dead here; spin-gates violate dispatch-
// order rules (deadlock risk). Ledger: best verified = ROUND 8 = 102.6us
// (37-block direct setup + LDS-staged main, rolled ks3, no rotation);
// round 10's 9-block setup + rotation cost ~5us. Round 13 = round 8 restored
// EXACTLY + T5 s_setprio(1/0) around each ks3's 32-MFMA burst (zero-risk,
// 2 SALU/iter): waves drift after the staging barrier, so boosting the
// MFMA-phase wave lets it own the matrix pipe while siblings run pack/init
// VALU (MfmaUtil 37 + VALUBusy 36, currently non-overlapping).
// Permutation identity (HW-verified rounds 4-11):
//   h2 feature(slot) = 32*quad + mt*4 + r  (phase-2 D)  =  32*quad + ks3*8 + j
//   (phase-3 B), so phase-2 output regs ARE phase-3 B-frags.

typedef _Float16 f16;
typedef __attribute__((ext_vector_type(2))) _Float16 h2v;
typedef __attribute__((ext_vector_type(8))) _Float16 half8;
typedef __attribute__((ext_vector_type(4))) float floatx4;

#define H 128
#define NS 64

static __device__ __forceinline__ h2v pkrtz(float a, float b) {
  return __builtin_bit_cast(h2v, __builtin_amdgcn_cvt_pkrtz(a, b));
}

// x += dpp_shifted(x) with 0-fill; CTRL/RM compile-time (builtin needs ICE).
template <int CTRL, int RM>
static __device__ __forceinline__ float dpp_add(float x) {
  int sh = __builtin_amdgcn_update_dpp(0, __builtin_bit_cast(int, x),
                                       CTRL, RM, 0xf, false);
  return x + __builtin_bit_cast(float, sh);
}

// Wave64 inclusive add-scan, pure VALU (classic gfx9 sequence).
static __device__ __forceinline__ float wave_iscan(float x) {
  x = dpp_add<0x111, 0xf>(x);   // row_shr:1
  x = dpp_add<0x112, 0xf>(x);   // row_shr:2
  x = dpp_add<0x114, 0xf>(x);   // row_shr:4
  x = dpp_add<0x118, 0xf>(x);   // row_shr:8
  x = dpp_add<0x142, 0xa>(x);   // row_bcast:15 -> rows 1,3
  x = dpp_add<0x143, 0xc>(x);   // row_bcast:31 -> rows 2,3
  return x;
}

// ---------------------------------------------------------------------------
// Setup (round-8 version verbatim — part of the 102.6us-proven config):
// W2 -> A-frags with permuted cols n = 32*(l16>>2) + mt*4 + (l16&3);
// W3 -> A-frags with matching permuted rows k3 = 32*(lane>>4) + ks*8 + j
// (cols padded to 16). 37 blocks x 256 threads, direct scattered gathers.
// ---------------------------------------------------------------------------
__global__ void nerf_setup(const float* __restrict__ W2, const float* __restrict__ W3,
                           f16* __restrict__ wsW2, f16* __restrict__ wsW3) {
  int t = blockIdx.x * blockDim.x + threadIdx.x;
  if (t < 8192) {                       // W2 frags
    int j2 = t & 3, lane = (t >> 2) & 63, mt = (t >> 8) & 7, ks = t >> 11;
    int l16 = lane & 15;
    int k = ks * 32 + ((lane >> 4) * 8) + 2 * j2;
    int n = 32 * (l16 >> 2) + mt * 4 + (l16 & 3);    // permuted column
    wsW2[2 * t]     = (f16)W2[k * H + n];
    wsW2[2 * t + 1] = (f16)W2[(k + 1) * H + n];
  } else if (t < 9216) {                // W3 frags (A-layout, permuted rows, padded)
    int u = t - 8192;
    int j2 = u & 3, lane = (u >> 2) & 63, ks = u >> 8;
    int c = lane & 15;
    int k3 = 32 * (lane >> 4) + ks * 8 + 2 * j2;     // permuted h2 feature
    wsW3[2 * u]     = (c < 4) ? (f16)W3[k3 * 4 + c]       : (f16)0.0f;
    wsW3[2 * u + 1] = (c < 4) ? (f16)W3[(k3 + 1) * 4 + c] : (f16)0.0f;
  }
}

// ---------------------------------------------------------------------------
// Main: block = 8 rays = 8 waves; wave = 1 ray = 64 points.
// One barrier (after LDS weight staging); no other cross-wave deps.
// ---------------------------------------------------------------------------
__global__ __launch_bounds__(512, 4) void nerf_main(
    const float* __restrict__ origins, const float* __restrict__ dirs,
    const float* __restrict__ W1, const float* __restrict__ b1,
    const float* __restrict__ b2, const float* __restrict__ b3,
    const f16* __restrict__ ws,          // wsW2 (32 KB) ++ wsW3 (4 KB)
    float* __restrict__ out)
{
  __shared__ __align__(16) half8 w_lds[2304];     // 36 KB: W2 frags [0..2047], W3 [2048..2303]
  __shared__ __align__(16) float b2_lds[H];       // 512 B
  __shared__ __align__(16) f16   popd[8][2][H];   // per-wave po/pd strips (4 KB)
  __shared__ __align__(16) float f_lds[8][64][4]; // render transpose (8 KB)

  const int t = threadIdx.x;
  const int w = t >> 6, lane = t & 63, quad = lane >> 4, l16 = lane & 15;
  const float delta = 4.0f / NS;       // near=2, far=6 baked
  const int ray = blockIdx.x * 8 + w;

  // ---- Stage weights into LDS (2304 x 16 B = 4.5 per thread) ----
  {
    const uint4* src = (const uint4*)ws;
    uint4* dst = (uint4*)w_lds;
    #pragma unroll
    for (int i = 0; i < 4; ++i) dst[t + i * 512] = src[t + i * 512];
    if (t < 256) dst[t + 2048] = src[t + 2048];
    if (t < 32)  ((float4*)b2_lds)[t] = ((const float4*)b2)[t];
  }

  // ---- po/pd: po[k] = o@W1[:,k]+b1[k], pd[k] = d@W1[:,k]; f16 to LDS ----
  {
    const float o0 = origins[ray*3], o1 = origins[ray*3+1], o2 = origins[ray*3+2];
    const float d0 = dirs[ray*3],    d1 = dirs[ray*3+1],    d2 = dirs[ray*3+2];
    const int k0 = lane * 2;
    const float2 wr0 = *(const float2*)&W1[0*H + k0];
    const float2 wr1 = *(const float2*)&W1[1*H + k0];
    const float2 wr2 = *(const float2*)&W1[2*H + k0];
    const float2 bb  = *(const float2*)&b1[k0];
    float poa = fmaf(o2, wr2.x, fmaf(o1, wr1.x, fmaf(o0, wr0.x, bb.x)));
    float pob = fmaf(o2, wr2.y, fmaf(o1, wr1.y, fmaf(o0, wr0.y, bb.y)));
    float pda = fmaf(d2, wr2.x, fmaf(d1, wr1.x, d0 * wr0.x));
    float pdb = fmaf(d2, wr2.y, fmaf(d1, wr1.y, d0 * wr0.y));
    h2v po2; po2[0] = (f16)poa; po2[1] = (f16)pob;
    h2v pd2; pd2[0] = (f16)pda; pd2[1] = (f16)pdb;
    *(h2v*)&popd[w][0][k0] = po2;
    *(h2v*)&popd[w][1][k0] = pd2;
  }

  // ---- hb precompute: hb[ks2][tr] = relu(po + m*pd), resident 64 VGPRs ----
  // m exact in f16 (multiple of 1/32); sample s = tr*16 + l16.
  half8 hb[4][4];
  {
    const half8 z8 = (half8)(f16)0.0f;
    half8 m8[4];
    #pragma unroll
    for (int tr = 0; tr < 4; ++tr)
      m8[tr] = (half8)(f16)(2.0f + (tr*16 + l16 + 0.5f) * delta);
    #pragma unroll
    for (int ks = 0; ks < 4; ++ks) {
      const half8 po8 = *(const half8*)&popd[w][0][ks*32 + quad*8];
      const half8 pd8 = *(const half8*)&popd[w][1][ks*32 + quad*8];
      #pragma unroll
      for (int tr = 0; tr < 4; ++tr)
        hb[ks][tr] = __builtin_elementwise_max(pd8 * m8[tr] + po8, z8);
    }
  }

  __syncthreads();                       // weights staged

  const half8* w2f = w_lds;              // 2048 frags
  const half8* w3f = w_lds + 2048;       // 256 frags
  const h2v z2 = (h2v)(f16)0.0f;

  // acc3 init = b3 broadcast (quad 0 rows are the only consumed ones; W3
  // cols >=4 are zero-padded so other quads are garbage-but-unused).
  floatx4 acc3[4];
  {
    const float4 b3v = *(const float4*)&b3[0];
    #pragma unroll
    for (int tr = 0; tr < 4; ++tr) {
      acc3[tr][0] = b3v.x; acc3[tr][1] = b3v.y;
      acc3[tr][2] = b3v.z; acc3[tr][3] = b3v.w;
    }
  }

  // ---- Fused phase 2+3, mt-pair outer, ROLLED (4 iters, reg-safe).
  // T5: s_setprio(1) around the 32-MFMA phase-2 burst — waves drift after
  // the staging barrier, so the MFMA-phase wave preempts siblings' VALU
  // phases on the shared SIMD. ----
  #pragma unroll 1
  for (int ks3 = 0; ks3 < 4; ++ks3) {
    const int mt0 = 2 * ks3, mt1 = mt0 + 1;
    // bias fold: acc[mt][tr][r] starts at b2[32*quad + 4*mt + r]
    const float4 bA = *(const float4*)&b2_lds[quad*32 + ks3*8];
    const float4 bB = *(const float4*)&b2_lds[quad*32 + ks3*8 + 4];
    const half8 w3k = w3f[ks3*64 + lane];
    floatx4 accA[4], accB[4];
    #pragma unroll
    for (int tr = 0; tr < 4; ++tr) {
      accA[tr][0] = bA.x; accA[tr][1] = bA.y; accA[tr][2] = bA.z; accA[tr][3] = bA.w;
      accB[tr][0] = bB.x; accB[tr][1] = bB.y; accB[tr][2] = bB.z; accB[tr][3] = bB.w;
    }
    __builtin_amdgcn_s_setprio(1);
    #pragma unroll
    for (int ks2 = 0; ks2 < 4; ++ks2) {
      const half8 wA = w2f[(ks2*8 + mt0)*64 + lane];
      const half8 wB = w2f[(ks2*8 + mt1)*64 + lane];
      #pragma unroll
      for (int tr = 0; tr < 4; ++tr) {
        accA[tr] = __builtin_amdgcn_mfma_f32_16x16x32_f16(wA, hb[ks2][tr], accA[tr], 0, 0, 0);
        accB[tr] = __builtin_amdgcn_mfma_f32_16x16x32_f16(wB, hb[ks2][tr], accB[tr], 0, 0, 0);
      }
    }
    __builtin_amdgcn_s_setprio(0);
    // pack (bias already in acc) + phase-3 MFMA; b covers features
    // 32*quad + 8*ks3 + 0..7 matching W3's permuted rows.
    #pragma unroll
    for (int tr = 0; tr < 4; ++tr) {
      h2v c0 = __builtin_elementwise_max(pkrtz(accA[tr][0], accA[tr][1]), z2);
      h2v c1 = __builtin_elementwise_max(pkrtz(accA[tr][2], accA[tr][3]), z2);
      h2v c2 = __builtin_elementwise_max(pkrtz(accB[tr][0], accB[tr][1]), z2);
      h2v c3 = __builtin_elementwise_max(pkrtz(accB[tr][2], accB[tr][3]), z2);
      half8 b = { c0[0], c0[1], c1[0], c1[1], c2[0], c2[1], c3[0], c3[1] };
      acc3[tr] = __builtin_amdgcn_mfma_f32_16x16x32_f16(w3k, b, acc3[tr], 0, 0, 0);
    }
  }

  // D3: lane holds f[m = quad*4+r][point tr*16+l16]; quad 0 rows 0..3 are
  // (R,G,B,sigma), b3 already folded in. Transpose via tiny f_lds (same
  // wave, no barrier).
  if (quad == 0) {
    #pragma unroll
    for (int tr = 0; tr < 4; ++tr) {
      float4 fv;
      fv.x = acc3[tr][0]; fv.y = acc3[tr][1];
      fv.z = acc3[tr][2]; fv.w = acc3[tr][3];
      *(float4*)&f_lds[w][tr*16 + l16][0] = fv;      // ds_write_b128
    }
  }

  // ---- Phase 4: volume rendering, lane = sample; DPP scan, no bpermute ----
  {
    const float4 fv = *(const float4*)&f_lds[w][lane][0];
    const float sigma = fv.w;
    const float alpha = 1.0f - __expf(-sigma * delta);
    const float S  = wave_iscan(sigma);              // inclusive prefix
    const float T  = __expf(-delta * (S - sigma));   // exclusive transmittance
    const float wt = alpha * T;
    const float sr = wave_iscan(wt * fv.x);          // lane 63 = total
    const float sg = wave_iscan(wt * fv.y);
    const float sb = wave_iscan(wt * fv.z);
    if (lane == 63) {
      out[ray*3+0] = sr; out[ray*3+1] = sg; out[ray*3+2] = sb;
    }
  }
}

extern "C" void kernel_launch(void* const* d_in, const int* in_sizes, int n_in,
                              void* d_out, int out_size, void* d_ws, size_t ws_size,
                              hipStream_t stream) {
  const float* origins = (const float*)d_in[0];
  const float* dirs    = (const float*)d_in[1];
  const float* W1      = (const float*)d_in[2];
  const float* b1      = (const float*)d_in[3];
  const float* W2      = (const float*)d_in[4];
  const float* b2      = (const float*)d_in[5];
  const float* W3      = (const float*)d_in[6];
  const float* b3      = (const float*)d_in[7];
  float* out = (float*)d_out;

  f16* wsW2 = (f16*)d_ws;          // 16384 f16 = 32 KB
  f16* wsW3 = wsW2 + 16384;        // 2048 f16  = 4 KB (contiguous with wsW2)

  nerf_setup<<<37, 256, 0, stream>>>(W2, W3, wsW2, wsW3);
  nerf_main<<<16384 / 8, 512, 0, stream>>>(
      origins, dirs, W1, b1, b2, b3, wsW2, out);
}